// Round 7
// baseline (6065.778 us; speedup 1.0000x reference)
//
#include <hip/hip_runtime.h>

constexpr int UNITS = 10;
constexpr int TIN = 50;
constexpr int TOUT = 3;
constexpr int G4 = 40;
constexpr int BLK = 256;

constexpr float NEG_LOG2E = -1.44269504088896341f;

typedef float floatx4 __attribute__((ext_vector_type(4)));

// ws layout (floats):
//   0    : R1p[4][10][12] (480)  R1p[g][u][j] = R1[u*40+g*10+j]*s(g), j<10 else 0
//   480  : W1p[4][12]     (48)   W1p[g][j]    = W1[g*10+j]*s(g)
//   528  : b1p[4][12]     (48)
//   576  : W2s[10][40]    (400)  scaled cols (i/f/o * -log2e)
//   976  : b2s[40]        (40)
//   1016 : R2q[10][10][4] (400)  R2q[u][v][ga] = R2[v*40+ga*10+u]*s(ga)
//   total 1416 floats = 5664 B
constexpr int WS_FLOATS = 1416;

__global__ void prep_weights(const float* __restrict__ W1, const float* __restrict__ R1,
                             const float* __restrict__ b1, const float* __restrict__ W2,
                             const float* __restrict__ R2, const float* __restrict__ b2,
                             float* __restrict__ ws)
{
    const int tid = threadIdx.x;
    for (int i = tid; i < 480; i += BLK) {
        const int gate = i / 120, r = i % 120, u = r / 12, j = r % 12;
        const float s = (gate == 2) ? 1.0f : NEG_LOG2E;
        ws[i] = (j < 10) ? R1[u * G4 + gate * 10 + j] * s : 0.0f;
    }
    for (int i = tid; i < 48; i += BLK) {
        const int gate = i / 12, j = i % 12;
        const float s = (gate == 2) ? 1.0f : NEG_LOG2E;
        ws[480 + i] = (j < 10) ? W1[gate * 10 + j] * s : 0.0f;
        ws[528 + i] = (j < 10) ? b1[gate * 10 + j] * s : 0.0f;
    }
    for (int i = tid; i < 400; i += BLK) {
        const int col = i % G4;
        const float s2 = (col >= 20 && col < 30) ? 1.0f : NEG_LOG2E;
        ws[576 + i] = W2[i] * s2;
        const int u = i / 40, r = i % 40, v = r / 4, ga = r % 4;
        const float s3 = (ga == 2) ? 1.0f : NEG_LOG2E;
        ws[1016 + i] = R2[v * G4 + ga * 10 + u] * s3;
    }
    for (int i = tid; i < 40; i += BLK) {
        const float s2 = (i >= 20 && i < 30) ? 1.0f : NEG_LOG2E;
        ws[976 + i] = b2[i] * s2;
    }
}

__device__ __forceinline__ float sig_pre(float zs) {
    // zs prescaled by -log2(e): sigmoid(z) = 1/(1+2^zs); v_exp_f32 computes 2^x
    return __builtin_amdgcn_rcpf(1.0f + __builtin_amdgcn_exp2f(zs));
}

__global__ __launch_bounds__(BLK) void lstm_ae_kernel(
    const float* __restrict__ X, const float* __restrict__ ws,
    const float* __restrict__ Wd, const float* __restrict__ bd,
    float* __restrict__ out, int B)
{
    __shared__ __align__(16) float s[WS_FLOATS];
    for (int i = threadIdx.x; i < WS_FLOATS; i += BLK) s[i] = ws[i];
    __syncthreads();

    const float* __restrict__ sR1 = s;
    const float* __restrict__ sW1 = s + 480;
    const float* __restrict__ sb1 = s + 528;
    const float* __restrict__ sW2 = s + 576;
    const float* __restrict__ sb2 = s + 976;
    const float* __restrict__ sR2 = s + 1016;

    // M=2 thread coarsening: each thread runs rows b0 and b1.
    const int base = blockIdx.x * (2 * BLK);
    const int b0 = base + threadIdx.x;
    if (b0 >= B) return;
    int b1 = base + BLK + threadIdx.x;
    if (b1 >= B) b1 = b0;                 // clamp (B divides evenly in practice)

    float h0[UNITS], h1[UNITS], c0[UNITS], c1[UNITS];
    #pragma unroll
    for (int u = 0; u < UNITS; ++u) { h0[u]=0.f; h1[u]=0.f; c0[u]=0.f; c1[u]=0.f; }

    // One gate-chunk of the pre-activation dot product, both rows, quad LDS reads.
#define CHUNK(G, ZA, ZB, xA, xB)                                              \
    {                                                                         \
        const floatx4* __restrict__ Wq = (const floatx4*)(sW1 + (G) * 12);    \
        const floatx4* __restrict__ Bq = (const floatx4*)(sb1 + (G) * 12);    \
        _Pragma("unroll")                                                     \
        for (int q = 0; q < 3; ++q) {                                         \
            const floatx4 wv = Wq[q], bv = Bq[q];                             \
            _Pragma("unroll")                                                 \
            for (int e = 0; e < 4; ++e) {                                     \
                const int j = q * 4 + e;                                      \
                if (j < 10) {                                                 \
                    ZA[j] = fmaf(xA, wv[e], bv[e]);                           \
                    ZB[j] = fmaf(xB, wv[e], bv[e]);                           \
                }                                                             \
            }                                                                 \
        }                                                                     \
        _Pragma("unroll")                                                     \
        for (int u = 0; u < UNITS; ++u) {                                     \
            const floatx4* __restrict__ Rq =                                  \
                (const floatx4*)(sR1 + (G) * 120 + u * 12);                   \
            const float ha = h0[u], hb = h1[u];                               \
            _Pragma("unroll")                                                 \
            for (int q = 0; q < 3; ++q) {                                     \
                const floatx4 rv = Rq[q];                                     \
                _Pragma("unroll")                                             \
                for (int e = 0; e < 4; ++e) {                                 \
                    const int j = q * 4 + e;                                  \
                    if (j < 10) {                                             \
                        ZA[j] = fmaf(ha, rv[e], ZA[j]);                       \
                        ZB[j] = fmaf(hb, rv[e], ZB[j]);                       \
                    }                                                         \
                }                                                             \
            }                                                                 \
        }                                                                     \
    }

#define STEP(xA, xB)                                                          \
    {                                                                         \
        float za[10], zb[10], pa[10], pb[10];                                 \
        CHUNK(2, za, zb, xA, xB)   /* g-gate: relu */                         \
        _Pragma("unroll")                                                     \
        for (int j = 0; j < 10; ++j) { pa[j] = fmaxf(za[j], 0.f);             \
                                       pb[j] = fmaxf(zb[j], 0.f); }           \
        CHUNK(0, za, zb, xA, xB)   /* i-gate */                               \
        _Pragma("unroll")                                                     \
        for (int j = 0; j < 10; ++j) { pa[j] *= sig_pre(za[j]);               \
                                       pb[j] *= sig_pre(zb[j]); }             \
        CHUNK(1, za, zb, xA, xB)   /* f-gate */                               \
        _Pragma("unroll")                                                     \
        for (int j = 0; j < 10; ++j) { c0[j] = fmaf(sig_pre(za[j]), c0[j], pa[j]); \
                                       c1[j] = fmaf(sig_pre(zb[j]), c1[j], pb[j]); } \
        CHUNK(3, za, zb, xA, xB)   /* o-gate (reads old h) */                 \
        _Pragma("unroll")                                                     \
        for (int j = 0; j < 10; ++j) { h0[j] = sig_pre(za[j]) * fmaxf(c0[j], 0.f); \
                                       h1[j] = sig_pre(zb[j]) * fmaxf(c1[j], 0.f); } \
    }

    // x: float2 loads, one pair-iteration of software prefetch
    const float2* __restrict__ xpa = (const float2*)(X + (size_t)b0 * TIN);
    const float2* __restrict__ xpb = (const float2*)(X + (size_t)b1 * TIN);
    float2 va = xpa[0], vb = xpb[0];
    #pragma unroll 1
    for (int p = 0; p < TIN / 2 - 1; ++p) {
        const float2 na = xpa[p + 1], nb = xpb[p + 1];
        STEP(va.x, vb.x)
        STEP(va.y, vb.y)
        va = na; vb = nb;
    }
    STEP(va.x, vb.x)
    STEP(va.y, vb.y)
#undef STEP
#undef CHUNK

    // ---------------- RepeatVector(3) + LSTM 2 + Dense, per element --------
    const float wd0 = bd[0];
    #pragma unroll 1
    for (int m = 0; m < 2; ++m) {
        const float* __restrict__ hm = (m == 0) ? h0 : h1;
        const int brow = (m == 0) ? b0 : b1;

        // xz = hm @ W2s + b2s (quad reads over g)
        float xz[G4];
        #pragma unroll
        for (int q = 0; q < 10; ++q) {
            floatx4 a = ((const floatx4*)sb2)[q];
            #pragma unroll
            for (int u = 0; u < UNITS; ++u) {
                const floatx4 wv = ((const floatx4*)(sW2 + u * G4))[q];
                const float hu = hm[u];
                a[0] = fmaf(hu, wv[0], a[0]);
                a[1] = fmaf(hu, wv[1], a[1]);
                a[2] = fmaf(hu, wv[2], a[2]);
                a[3] = fmaf(hu, wv[3], a[3]);
            }
            xz[q * 4 + 0] = a[0]; xz[q * 4 + 1] = a[1];
            xz[q * 4 + 2] = a[2]; xz[q * 4 + 3] = a[3];
        }

        float h2[UNITS], c2[UNITS], o0;
        {   // t2 = 0: h_prev = c_prev = 0
            float acc = wd0;
            #pragma unroll
            for (int u = 0; u < UNITS; ++u) {
                const float ig = sig_pre(xz[u]);
                const float gg = fmaxf(xz[2 * UNITS + u], 0.f);
                const float og = sig_pre(xz[3 * UNITS + u]);
                const float cn = ig * gg;
                c2[u] = cn;
                const float hn = og * fmaxf(cn, 0.f);
                h2[u] = hn;
                acc = fmaf(hn, Wd[u], acc);
            }
            o0 = acc;
        }

        float oacc[2];
        #pragma unroll
        for (int t2 = 0; t2 < 2; ++t2) {
            float hold[UNITS];
            #pragma unroll
            for (int u = 0; u < UNITS; ++u) hold[u] = h2[u];
            float acc = wd0;
            #pragma unroll
            for (int u = 0; u < UNITS; ++u) {
                float zi = xz[u];
                float zf = xz[UNITS + u];
                float zg = xz[2 * UNITS + u];
                float zo = xz[3 * UNITS + u];
                #pragma unroll
                for (int v = 0; v < UNITS; ++v) {
                    // R2q[u][v][i,f,g,o] — one quad per (u,v)
                    const floatx4 rv = *(const floatx4*)(sR2 + u * G4 + v * 4);
                    const float hv = hold[v];
                    zi = fmaf(hv, rv[0], zi);
                    zf = fmaf(hv, rv[1], zf);
                    zg = fmaf(hv, rv[2], zg);
                    zo = fmaf(hv, rv[3], zo);
                }
                const float ig = sig_pre(zi);
                const float fg = sig_pre(zf);
                const float gg = fmaxf(zg, 0.f);
                const float og = sig_pre(zo);
                const float cn = fmaf(fg, c2[u], ig * gg);
                c2[u] = cn;
                const float hn = og * fmaxf(cn, 0.f);
                h2[u] = hn;
                acc = fmaf(hn, Wd[u], acc);
            }
            oacc[t2] = acc;
        }

        float* __restrict__ o3 = out + (size_t)brow * TOUT;
        o3[0] = o0;
        o3[1] = oacc[0];
        o3[2] = oacc[1];
    }
}

extern "C" void kernel_launch(void* const* d_in, const int* in_sizes, int n_in,
                              void* d_out, int out_size, void* d_ws, size_t ws_size,
                              hipStream_t stream) {
    const float* X  = (const float*)d_in[0];
    const float* W1 = (const float*)d_in[1];
    const float* R1 = (const float*)d_in[2];
    const float* b1 = (const float*)d_in[3];
    const float* W2 = (const float*)d_in[4];
    const float* R2 = (const float*)d_in[5];
    const float* b2 = (const float*)d_in[6];
    const float* Wd = (const float*)d_in[7];
    const float* bd = (const float*)d_in[8];
    float* out = (float*)d_out;
    float* ws  = (float*)d_ws;

    const int B = in_sizes[0] / TIN;   // 524288
    prep_weights<<<1, BLK, 0, stream>>>(W1, R1, b1, W2, R2, b2, ws);
    const int grid = (B + 2 * BLK - 1) / (2 * BLK);   // 1024
    lstm_ae_kernel<<<grid, BLK, 0, stream>>>(X, ws, Wd, bd, out, B);
}